// Round 13
// baseline (695.483 us; speedup 1.0000x reference)
//
#include <hip/hip_runtime.h>
#include <hip/hip_bf16.h>
#include <hip/hip_cooperative_groups.h>
#include <stdint.h>

namespace cg = cooperative_groups;

#define D_ 128
#define NB 64      // index rows per chunk
#define GB 512     // cooperative grid blocks (2 per CU on 256-CU MI355X)
#define NINF (-__builtin_inff())

typedef float f32x4 __attribute__((ext_vector_type(4)));
typedef short bf16x8 __attribute__((ext_vector_type(8)));

__device__ inline unsigned short f2bf(float f){
  unsigned x = __float_as_uint(f);
  return (unsigned short)((x + 0x7FFFu + ((x >> 16) & 1u)) >> 16);  // RNE
}
__device__ inline unsigned packbf(float a, float b){
  return (unsigned)f2bf(a) | ((unsigned)f2bf(b) << 16);
}
// monotonic float->u32 key for atomicMax (fallback path only)
__device__ inline unsigned fkey(float v){
  unsigned b = __float_as_uint(v);
  return (b & 0x80000000u) ? ~b : (b | 0x80000000u);
}

// normalize one 64-row unit (256 threads, 4/row) f32 -> bf16
__device__ inline void norm_unit(const float* __restrict__ src, unsigned short* __restrict__ dst,
                                 int r0, int t){
  int r = r0 + (t >> 2), j = t & 3;
  const f32x4* s4 = reinterpret_cast<const f32x4*>(src + (size_t)r * D_ + j * 32);
  f32x4 v[8];
  #pragma unroll
  for (int i = 0; i < 8; i++) v[i] = s4[i];
  float ss = 0.f;
  #pragma unroll
  for (int i = 0; i < 8; i++) ss += v[i][0]*v[i][0] + v[i][1]*v[i][1] + v[i][2]*v[i][2] + v[i][3]*v[i][3];
  ss += __shfl_xor(ss, 1); ss += __shfl_xor(ss, 2);
  float sc = 1.0f / fmaxf(sqrtf(ss), 1e-12f);
  unsigned o[16];
  #pragma unroll
  for (int i = 0; i < 8; i++){
    o[i*2]   = packbf(v[i][0]*sc, v[i][1]*sc);
    o[i*2+1] = packbf(v[i][2]*sc, v[i][3]*sc);
  }
  uint4* d4 = reinterpret_cast<uint4*>(dst + (size_t)r * D_ + j * 32);
  #pragma unroll
  for (int i = 0; i < 4; i++) d4[i] = make_uint4(o[i*4], o[i*4+1], o[i*4+2], o[i*4+3]);
}

// =============== single cooperative kernel: all phases, one node ============
__global__ __launch_bounds__(256, 2) void k_all(
    const float* __restrict__ emb, const float* __restrict__ x,
    const int* __restrict__ lab,
    unsigned short* __restrict__ nrmlin, unsigned short* __restrict__ xn,
    unsigned* __restrict__ phist, unsigned* __restrict__ hist,
    unsigned* __restrict__ cursor, unsigned* __restrict__ cbase,
    int* __restrict__ perm, float* __restrict__ out,
    int N, int B, int C){
  cg::grid_group grid = cg::this_grid();
  const int bid = blockIdx.x, t = threadIdx.x;
  const int nblk = (int)gridDim.x;
  const int w = t >> 6, lane = t & 63, lr = lane & 15, lg = lane >> 4;

  __shared__ __align__(16) unsigned short Ab[2][NB * D_];   // 32 KB, aliased per phase
  unsigned* lh = reinterpret_cast<unsigned*>(&Ab[0][0]);    // u32 view for hist/scan

  // ---- Phase A: normalize emb->nrmlin, x->xn; per-block partial histogram
  for (int c = t; c < 1024; c += 256) lh[c] = 0;
  __syncthreads();
  const int PN = N >> 6;                  // N multiple of 64 (checked host-side)
  const int XU = B >> 6;
  for (int u = bid; u < PN + XU; u += nblk){
    if (u < PN) norm_unit(emb, nrmlin, u * 64, t);
    else        norm_unit(x,   xn,    (u - PN) * 64, t);
  }
  for (int i = bid * 256 + t; i < N; i += nblk * 256) atomicAdd(&lh[lab[i]], 1u);
  __syncthreads();
  for (int c = t; c < C; c += 256) phist[(size_t)bid * 1024 + c] = lh[c];
  __threadfence();
  grid.sync();

  // ---- Phase B1: wave-per-class sum of partials -> hist
  {
    int gw = (bid << 2) + w;
    for (int c = gw; c < C; c += nblk * 4){
      int s = 0;
      for (int p = lane; p < nblk; p += 64) s += (int)phist[(size_t)p * 1024 + c];
      #pragma unroll
      for (int m = 32; m >= 1; m >>= 1) s += __shfl_xor(s, m);
      if (lane == 0) hist[c] = (unsigned)s;
    }
  }
  __threadfence();
  grid.sync();

  // ---- Phase B2: block-0 exclusive scan -> cursor (mutable) + cbase
  if (bid == 0){
    unsigned v[4]; unsigned s = 0;
    #pragma unroll
    for (int i = 0; i < 4; i++){ int c = t * 4 + i; v[i] = (c < C) ? hist[c] : 0u; s += v[i]; }
    lh[t] = s; __syncthreads();
    for (int off = 1; off < 256; off <<= 1){
      unsigned u2 = (t >= off) ? lh[t - off] : 0u;
      __syncthreads(); lh[t] += u2; __syncthreads();
    }
    unsigned run = lh[t] - s;
    #pragma unroll
    for (int i = 0; i < 4; i++){
      int c = t * 4 + i;
      if (c < C){ cursor[c] = run; cbase[c] = run; }
      run += v[i];
    }
  }
  __threadfence();
  grid.sync();

  // ---- Phase C: scatter -> class-sorted permutation
  for (int i = bid * 256 + t; i < N; i += nblk * 256){
    int c = lab[i];
    unsigned pos = atomicAdd(&cursor[c], 1u);
    perm[pos] = i;
  }
  __threadfence();
  grid.sync();

  // ---- Phase D: per-class GEMM + register max; zero atomics
  bf16x8 bf[4][4];
  #pragma unroll
  for (int ni = 0; ni < 4; ni++)
    #pragma unroll
    for (int kk = 0; kk < 4; kk++)
      bf[ni][kk] = *reinterpret_cast<const bf16x8*>(
          xn + (size_t)(w * 64 + ni * 16 + lr) * D_ + kk * 32 + lg * 8);

  for (int c = bid; c < C; c += nblk){
    const int nrows = (int)hist[c];
    if (nrows == 0){ out[(size_t)t * C + c] = NINF; continue; }
    const int base = (int)cbase[c];
    const int last = base + nrows - 1;
    const int chunks = (nrows + NB - 1) >> 6;

    auto rid_load = [&](int ci, int (&r)[4]){
      int cc = ci < chunks ? ci : chunks - 1;
      #pragma unroll
      for (int i = 0; i < 4; i++){
        int gr = base + cc * NB + i * 16 + lr;
        if (gr > last) gr = last;                  // same-class duplicate: max-neutral
        r[i] = perm[gr];
      }
    };
    auto stage = [&](int bb, const int (&r)[4]){
      #pragma unroll
      for (int i = 0; i < 4; i++){
        const char* src = (const char*)nrmlin + (size_t)r[i] * 256 + ((w * 4 + lg) << 4);
        char* dst = (char*)(&Ab[bb][0]) + (w + i * 4) * 1024 + lane * 16;
        __builtin_amdgcn_global_load_lds(
            (const __attribute__((address_space(1))) unsigned int*)src,
            (__attribute__((address_space(3))) unsigned int*)dst, 16, 0, 0);
      }
    };

    int ridN[4];
    rid_load(0, ridN);
    stage(0, ridN);
    rid_load(1, ridN);

    float M0 = NINF, M1 = NINF, M2 = NINF, M3 = NINF;

    for (int ci = 0; ci < chunks; ++ci){
      const int b = ci & 1;
      stage(b ^ 1, ridN);            // consuming ridN drains own gll(ci) (in-order vmcnt)
      rid_load(ci + 2, ridN);
      __builtin_amdgcn_s_barrier();  // Ab[b] staged by all waves

      f32x4 acc[4][4];
      #pragma unroll
      for (int mi = 0; mi < 4; mi++)
        #pragma unroll
        for (int ni = 0; ni < 4; ni++)
          acc[mi][ni] = (f32x4){0.f, 0.f, 0.f, 0.f};

      #pragma unroll
      for (int mi = 0; mi < 4; mi++)
        #pragma unroll
        for (int kk = 0; kk < 4; kk++){
          bf16x8 af = *reinterpret_cast<const bf16x8*>(&Ab[b][(mi * 4 + kk) * 512 + lane * 8]);
          #pragma unroll
          for (int ni = 0; ni < 4; ni++)
            acc[mi][ni] = __builtin_amdgcn_mfma_f32_16x16x32_bf16(af, bf[ni][kk], acc[mi][ni], 0, 0, 0);
        }
      __builtin_amdgcn_s_barrier();  // reads of Ab[b] done before next overwrite

      #pragma unroll
      for (int mi = 0; mi < 4; mi++)
        #pragma unroll
        for (int rg = 0; rg < 4; rg++){
          M0 = fmaxf(M0, acc[mi][0][rg]);
          M1 = fmaxf(M1, acc[mi][1][rg]);
          M2 = fmaxf(M2, acc[mi][2][rg]);
          M3 = fmaxf(M3, acc[mi][3][rg]);
        }
    }
    asm volatile("s_waitcnt vmcnt(0)" ::: "memory");  // drain tail prefetch before Ab reuse

    M0 = fmaxf(M0, __shfl_xor(M0, 16)); M0 = fmaxf(M0, __shfl_xor(M0, 32));
    M1 = fmaxf(M1, __shfl_xor(M1, 16)); M1 = fmaxf(M1, __shfl_xor(M1, 32));
    M2 = fmaxf(M2, __shfl_xor(M2, 16)); M2 = fmaxf(M2, __shfl_xor(M2, 32));
    M3 = fmaxf(M3, __shfl_xor(M3, 16)); M3 = fmaxf(M3, __shfl_xor(M3, 32));
    float mv = (lg < 2) ? ((lg == 0) ? M0 : M1) : ((lg == 2) ? M2 : M3);
    out[(size_t)t * C + c] = mv;
  }
}

// ================= fallback path (measured round-12 kernels) ================
__global__ void k_prep(const float* __restrict__ emb, const float* __restrict__ x,
                       unsigned short* __restrict__ nrmlin, unsigned short* __restrict__ xn,
                       const int* __restrict__ lab, unsigned* __restrict__ hist,
                       int N, int B, int C, int PN, int XB, int HB){
  const int bid = blockIdx.x;
  const int t = threadIdx.x;
  if (bid < PN + XB){
    if (bid < PN) norm_unit(emb, nrmlin, bid * 64, t);
    else          norm_unit(x,   xn,    (bid - PN) * 64, t);
  } else {
    int hb = bid - PN - XB;
    __shared__ unsigned lh[1024];
    for (int c = t; c < 1024; c += 256) lh[c] = 0;
    __syncthreads();
    for (int i = hb * 256 + t; i < N; i += HB * 256) atomicAdd(&lh[lab[i]], 1u);
    __syncthreads();
    for (int c = t; c < C; c += 256){ unsigned v = lh[c]; if (v) atomicAdd(&hist[c], v); }
  }
}

__global__ void k_scan(const unsigned* __restrict__ hist, unsigned* __restrict__ cursor,
                       unsigned* __restrict__ cbase, int C){
  __shared__ unsigned s[1024];
  int t = threadIdx.x;
  unsigned v = (t < C) ? hist[t] : 0u;
  s[t] = v; __syncthreads();
  for (int off = 1; off < 1024; off <<= 1){
    unsigned u = (t >= off) ? s[t - off] : 0u;
    __syncthreads();
    s[t] += u;
    __syncthreads();
  }
  if (t < C){ unsigned e = s[t] - v; cursor[t] = e; cbase[t] = e; }
}

__global__ void k_scatter(const int* __restrict__ lab, unsigned* __restrict__ cursor,
                          int* __restrict__ perm, int* __restrict__ slab, int N){
  for (int i = blockIdx.x * 256 + threadIdx.x; i < N; i += gridDim.x * 256){
    int c = lab[i];
    unsigned pos = atomicAdd(&cursor[c], 1u);
    perm[pos] = i;
    slab[pos] = c;
  }
}

__global__ __launch_bounds__(256, 2) void k_gemm_cls(
    const unsigned short* __restrict__ nrmlin,
    const unsigned short* __restrict__ xn,
    const int* __restrict__ perm,
    const unsigned* __restrict__ cbase, const unsigned* __restrict__ hist,
    float* __restrict__ out, int N, int C){
  const int c = blockIdx.x;
  const int t = threadIdx.x, w = t >> 6, lane = t & 63, lr = lane & 15, lg = lane >> 4;
  const int nrows = (int)hist[c];
  if (nrows == 0){ out[(size_t)t * C + c] = NINF; return; }
  const int base = (int)cbase[c];
  const int last = base + nrows - 1;
  const int chunks = (nrows + NB - 1) >> 6;

  __shared__ __align__(16) unsigned short Ab[2][NB * D_];

  auto rid_load = [&](int ci, int (&r)[4]){
    int cc = ci < chunks ? ci : chunks - 1;
    #pragma unroll
    for (int i = 0; i < 4; i++){
      int gr = base + cc * NB + i * 16 + lr;
      if (gr > last) gr = last;
      r[i] = perm[gr];
    }
  };
  auto stage = [&](int bb, const int (&r)[4]){
    #pragma unroll
    for (int i = 0; i < 4; i++){
      const char* src = (const char*)nrmlin + (size_t)r[i] * 256 + ((w * 4 + lg) << 4);
      char* dst = (char*)(&Ab[bb][0]) + (w + i * 4) * 1024 + lane * 16;
      __builtin_amdgcn_global_load_lds(
          (const __attribute__((address_space(1))) unsigned int*)src,
          (__attribute__((address_space(3))) unsigned int*)dst, 16, 0, 0);
    }
  };

  int ridN[4];
  rid_load(0, ridN);
  stage(0, ridN);
  rid_load(1, ridN);

  bf16x8 bf[4][4];
  #pragma unroll
  for (int ni = 0; ni < 4; ni++)
    #pragma unroll
    for (int kk = 0; kk < 4; kk++)
      bf[ni][kk] = *reinterpret_cast<const bf16x8*>(
          xn + (size_t)(w * 64 + ni * 16 + lr) * D_ + kk * 32 + lg * 8);

  float M0 = NINF, M1 = NINF, M2 = NINF, M3 = NINF;

  for (int ci = 0; ci < chunks; ++ci){
    const int b = ci & 1;
    stage(b ^ 1, ridN);
    rid_load(ci + 2, ridN);
    __builtin_amdgcn_s_barrier();

    f32x4 acc[4][4];
    #pragma unroll
    for (int mi = 0; mi < 4; mi++)
      #pragma unroll
      for (int ni = 0; ni < 4; ni++)
        acc[mi][ni] = (f32x4){0.f, 0.f, 0.f, 0.f};

    #pragma unroll
    for (int mi = 0; mi < 4; mi++)
      #pragma unroll
      for (int kk = 0; kk < 4; kk++){
        bf16x8 af = *reinterpret_cast<const bf16x8*>(&Ab[b][(mi * 4 + kk) * 512 + lane * 8]);
        #pragma unroll
        for (int ni = 0; ni < 4; ni++)
          acc[mi][ni] = __builtin_amdgcn_mfma_f32_16x16x32_bf16(af, bf[ni][kk], acc[mi][ni], 0, 0, 0);
      }
    __builtin_amdgcn_s_barrier();

    #pragma unroll
    for (int mi = 0; mi < 4; mi++)
      #pragma unroll
      for (int rg = 0; rg < 4; rg++){
        M0 = fmaxf(M0, acc[mi][0][rg]);
        M1 = fmaxf(M1, acc[mi][1][rg]);
        M2 = fmaxf(M2, acc[mi][2][rg]);
        M3 = fmaxf(M3, acc[mi][3][rg]);
      }
  }
  asm volatile("s_waitcnt vmcnt(0)" ::: "memory");

  M0 = fmaxf(M0, __shfl_xor(M0, 16)); M0 = fmaxf(M0, __shfl_xor(M0, 32));
  M1 = fmaxf(M1, __shfl_xor(M1, 16)); M1 = fmaxf(M1, __shfl_xor(M1, 32));
  M2 = fmaxf(M2, __shfl_xor(M2, 16)); M2 = fmaxf(M2, __shfl_xor(M2, 32));
  M3 = fmaxf(M3, __shfl_xor(M3, 16)); M3 = fmaxf(M3, __shfl_xor(M3, 32));
  float mv = (lg < 2) ? ((lg == 0) ? M0 : M1) : ((lg == 2) ? M2 : M3);
  out[(size_t)t * C + c] = mv;
}

__global__ void k_init_out(unsigned* __restrict__ o, int n){
  int i = blockIdx.x * 256 + threadIdx.x;
  if (i < n) o[i] = 0x007FFFFFu;
}

struct __align__(16) GSm {
  unsigned short A[NB * 136];
  float sims[16 * 257];
  float scale[NB];
  int rowid[NB];
  int clab[NB];
};

__global__ __launch_bounds__(256, 2) void k_gemm_gather(
    const float* __restrict__ emb, const unsigned short* __restrict__ xn,
    const int* __restrict__ perm, const int* __restrict__ slab,
    unsigned* __restrict__ out_u, int N, int C){
  __shared__ GSm sm;
  const int t = threadIdx.x;
  const int base = blockIdx.x * NB;
  if (t < NB){
    int p = base + t; if (p > N - 1) p = N - 1;
    sm.rowid[t] = perm[p];
    sm.clab[t]  = slab[p];
  }
  __syncthreads();
  {
    int r = t >> 2, j = t & 3;
    const float4* src = reinterpret_cast<const float4*>(emb + (long)sm.rowid[r] * D_ + j * 32);
    float4 v[8];
    #pragma unroll
    for (int i = 0; i < 8; i++) v[i] = src[i];
    float ss = 0.f;
    #pragma unroll
    for (int i = 0; i < 8; i++) ss += v[i].x*v[i].x + v[i].y*v[i].y + v[i].z*v[i].z + v[i].w*v[i].w;
    ss += __shfl_xor(ss, 1); ss += __shfl_xor(ss, 2);
    sm.scale[r] = 1.0f / fmaxf(sqrtf(ss), 1e-12f);
    unsigned* dst = reinterpret_cast<unsigned*>(&sm.A[r * 136 + j * 32]);
    #pragma unroll
    for (int i = 0; i < 8; i++){
      dst[i * 2]     = packbf(v[i].x, v[i].y);
      dst[i * 2 + 1] = packbf(v[i].z, v[i].w);
    }
  }
  const int w = t >> 6, lane = t & 63;
  const int lr = lane & 15, lg = lane >> 4;
  bf16x8 bfr[4][4];
  #pragma unroll
  for (int ni = 0; ni < 4; ni++)
    #pragma unroll
    for (int kk = 0; kk < 4; kk++)
      bfr[ni][kk] = *reinterpret_cast<const bf16x8*>(
          xn + (size_t)(w * 64 + ni * 16 + lr) * D_ + kk * 32 + lg * 8);
  f32x4 acc[4][4];
  #pragma unroll
  for (int mi = 0; mi < 4; mi++)
    #pragma unroll
    for (int ni = 0; ni < 4; ni++)
      acc[mi][ni] = (f32x4){0.f, 0.f, 0.f, 0.f};
  __syncthreads();
  #pragma unroll
  for (int mi = 0; mi < 4; mi++)
    #pragma unroll
    for (int kk = 0; kk < 4; kk++){
      bf16x8 af = *reinterpret_cast<const bf16x8*>(&sm.A[(mi * 16 + lr) * 136 + kk * 32 + lg * 8]);
      #pragma unroll
      for (int ni = 0; ni < 4; ni++)
        acc[mi][ni] = __builtin_amdgcn_mfma_f32_16x16x32_bf16(af, bfr[ni][kk], acc[mi][ni], 0, 0, 0);
    }
  int cur = -1; float rm = 0.f;
  for (int mi = 0; mi < 4; mi++){
    __syncthreads();
    #pragma unroll
    for (int ni = 0; ni < 4; ni++)
      #pragma unroll
      for (int rg = 0; rg < 4; rg++){
        int r16 = lg * 4 + rg;
        sm.sims[r16 * 257 + w * 64 + ni * 16 + lr] = acc[mi][ni][rg] * sm.scale[mi * 16 + r16];
      }
    __syncthreads();
    #pragma unroll
    for (int r16 = 0; r16 < 16; r16++){
      int cc = sm.clab[mi * 16 + r16];
      float v = sm.sims[r16 * 257 + t];
      if (cc != cur){
        if (cur >= 0) atomicMax(&out_u[(size_t)t * C + cur], fkey(rm));
        cur = cc; rm = v;
      } else rm = fmaxf(rm, v);
    }
  }
  atomicMax(&out_u[(size_t)t * C + cur], fkey(rm));
}

__global__ void k_finalize(unsigned* __restrict__ o, int n){
  int i = blockIdx.x * 256 + threadIdx.x;
  if (i < n){
    unsigned k = o[i];
    o[i] = (k & 0x80000000u) ? (k & 0x7FFFFFFFu) : ~k;
  }
}

extern "C" void kernel_launch(void* const* d_in, const int* in_sizes, int n_in,
                              void* d_out, int out_size, void* d_ws, size_t ws_size,
                              hipStream_t stream){
  const float* x   = (const float*)d_in[0];
  const float* emb = (const float*)d_in[1];
  const int*   lab = (const int*)d_in[2];
  const int B = in_sizes[0] / D_;        // 256
  const int N = in_sizes[1] / D_;        // 200000
  const int C = out_size / B;            // 1000

  const int PNfull = (N + 63) / 64;
  const int XB = (B + 63) / 64;
  const int HB = 208;

  char* ws = (char*)d_ws;
  size_t off = 0;
  unsigned short* xn = (unsigned short*)(ws); off += ((size_t)B * D_ * 2 + 255) & ~(size_t)255;
  unsigned* hist   = (unsigned*)(ws + off); off += 4096;
  unsigned* cursor = (unsigned*)(ws + off); off += 4096;
  unsigned* cbase  = (unsigned*)(ws + off); off += 4096;
  unsigned* phist  = (unsigned*)(ws + off); off += (size_t)GB * 1024 * 4;   // 2 MB
  size_t narr = ((size_t)N * 4 + 255) & ~(size_t)255;
  int* perm   = (int*)(ws + off); off += narr;
  int* slab   = (int*)(ws + off); off += narr;
  unsigned short* nrmlin = (unsigned short*)(ws + off);
  size_t need = off + (size_t)N * D_ * 2;
  const bool fast = (ws_size >= need);

  // -------- preferred: single cooperative node --------
  bool coop_ok = false;
  if (fast && B == 256 && C <= 1000 && (N & 63) == 0 && (B & 63) == 0){
    const float* a_emb = emb; const float* a_x = x; const int* a_lab = lab;
    unsigned short* a_nrm = nrmlin; unsigned short* a_xn = xn;
    unsigned* a_ph = phist; unsigned* a_h = hist; unsigned* a_cur = cursor; unsigned* a_cb = cbase;
    int* a_perm = perm; float* a_out = (float*)d_out;
    int a_N = N, a_B = B, a_C = C;
    void* args[] = {(void*)&a_emb, (void*)&a_x, (void*)&a_lab, (void*)&a_nrm, (void*)&a_xn,
                    (void*)&a_ph, (void*)&a_h, (void*)&a_cur, (void*)&a_cb,
                    (void*)&a_perm, (void*)&a_out, (void*)&a_N, (void*)&a_B, (void*)&a_C};
    hipError_t e = hipLaunchCooperativeKernel((void*)k_all, dim3(GB), dim3(256),
                                              args, 0, stream);
    coop_ok = (e == hipSuccess);
    if (!coop_ok) (void)hipGetLastError();   // clear sticky error for fallback
  }

  if (!coop_ok){
    // -------- fallback: measured round-12 multi-node path --------
    hipMemsetAsync(hist, 0, 4096, stream);
    const int PN = fast ? PNfull : 0;
    k_prep<<<PN + XB + HB, 256, 0, stream>>>(emb, x, nrmlin, xn, lab, hist,
                                             N, B, C, PN, XB, HB);
    k_scan<<<1, 1024, 0, stream>>>(hist, cursor, cbase, C);
    k_scatter<<<208, 256, 0, stream>>>(lab, cursor, perm, slab, N);
    if (fast){
      k_gemm_cls<<<C, 256, 0, stream>>>(nrmlin, xn, perm, cbase, hist,
                                        (float*)d_out, N, C);
    } else {
      const int IB = (B * C + 255) / 256;
      k_init_out<<<IB, 256, 0, stream>>>((unsigned*)d_out, B * C);
      k_gemm_gather<<<PNfull, 256, 0, stream>>>(emb, xn, perm, slab, (unsigned*)d_out, N, C);
      k_finalize<<<IB, 256, 0, stream>>>((unsigned*)d_out, B * C);
    }
  }
}